// Round 1
// baseline (543.458 us; speedup 1.0000x reference)
//
#include <hip/hip_runtime.h>
#include <cmath>

namespace {

constexpr int NS = 16;    // samples per block
constexpr int NT = 256;   // threads per block
constexpr int ED = 32;    // embed dim (channels)
constexpr int NF = 16;    // filters
constexpr int PCHUNK = 12; // positions per register chunk

// Each thread owns (sample s, filter f). Processes one input (compile-time I, L):
// stage x tile to LDS, then for each position-chunk keep acc[5][PCHUNK] in regs,
// loop channels, reuse each x row across all 5 kernel sizes.
template<int I, int L>
__device__ __forceinline__ void process_input(
    const float* __restrict__ xi,
    const float* const* __restrict__ ws,
    const float* const* __restrict__ cs,
    const float* __restrict__ dw,
    float* __restrict__ tile,
    int t, int s, int f, int b0, float& dot)
{
  constexpr int Lp = L | 1;  // odd stride -> conflict-free LDS reads

  __syncthreads();  // protect previous input's tile
  // stage: x[b0+ss][c][l] -> tile[(c*NS+ss)*Lp + l], coalesced global reads
  for (int e = t; e < NS * ED * L; e += NT) {
    const int ss = e / (ED * L);
    const int r  = e - ss * (ED * L);
    const int c  = r / L;
    const int l  = r - c * L;
    tile[(c * NS + ss) * Lp + l] = xi[(b0 + ss) * (ED * L) + r];
  }
  __syncthreads();

  float bk[5], fk[5];
  #pragma unroll
  for (int kk = 0; kk < 5; ++kk) {
    bk[kk] = cs[kk][I * NF + f];   // bias for (input I, kernel k, filter f)
    fk[kk] = 0.0f;                 // running max (relu -> >= 0)
  }

  #pragma unroll
  for (int p0 = 0; p0 < L; p0 += PCHUNK) {
    const int PL  = (L - p0 < PCHUNK) ? (L - p0) : PCHUNK;
    const int qlo = (p0 >= 4) ? (p0 - 4) : 0;            // max half-width = 4 (k=9)
    const int qhi = (p0 + PL + 4 < L) ? (p0 + PL + 4) : L;

    float acc[5][PCHUNK];
    #pragma unroll
    for (int kk = 0; kk < 5; ++kk)
      #pragma unroll
      for (int p = 0; p < PCHUNK; ++p)
        acc[kk][p] = bk[kk];

    for (int c = 0; c < ED; ++c) {   // runtime loop (code-size control)
      const float* row = &tile[(c * NS + s) * Lp];
      float xr[PCHUNK + 8];
      #pragma unroll
      for (int q = 0; q < PCHUNK + 8; ++q)
        if (qlo + q < qhi) xr[q] = row[qlo + q];

      float wv[25];
      {
        int wo = 0;
        #pragma unroll
        for (int kk = 0; kk < 5; ++kk) {
          const int k = 2 * kk + 1;
          const float* wp = ws[kk] + ((I * NF + f) * ED + c) * k;
          #pragma unroll
          for (int t2 = 0; t2 < k; ++t2) wv[wo + t2] = wp[t2];
          wo += k;
        }
      }
      {
        int wo = 0;
        #pragma unroll
        for (int kk = 0; kk < 5; ++kk) {
          const int k = 2 * kk + 1;   // half-width = kk
          #pragma unroll
          for (int p = 0; p < PCHUNK; ++p) {
            if (p < PL) {
              #pragma unroll
              for (int t2 = 0; t2 < k; ++t2) {
                const int q = p0 + p + t2 - kk;
                if (q >= 0 && q < L)   // compile-time SAME-padding clipping
                  acc[kk][p] = fmaf(xr[q - qlo], wv[wo + t2], acc[kk][p]);
              }
            }
          }
          wo += k;
        }
      }
    }

    #pragma unroll
    for (int kk = 0; kk < 5; ++kk)
      #pragma unroll
      for (int p = 0; p < PCHUNK; ++p)
        if (p < PL) fk[kk] = fmaxf(fk[kk], acc[kk][p]);
  }

  #pragma unroll
  for (int kk = 0; kk < 5; ++kk)
    dot = fmaf(fmaxf(fk[kk], 0.0f), dw[(I * 5 + kk) * NF + f], dot);
}

__global__ __launch_bounds__(NT, 2) void nettcr_fused(
    const float* __restrict__ x0, const float* __restrict__ x1,
    const float* __restrict__ x2, const float* __restrict__ x3,
    const float* __restrict__ x4, const float* __restrict__ x5,
    const float* __restrict__ x6,
    const float* __restrict__ w1, const float* __restrict__ c1,
    const float* __restrict__ w3, const float* __restrict__ c3,
    const float* __restrict__ w5, const float* __restrict__ c5,
    const float* __restrict__ w7, const float* __restrict__ c7,
    const float* __restrict__ w9, const float* __restrict__ c9,
    const float* __restrict__ dw, const float* __restrict__ db,
    float* __restrict__ out)
{
  __shared__ float tile[ED * NS * 23];  // 47104 B, sized for L=23
  __shared__ float red[NT];

  const int t  = threadIdx.x;
  const int s  = t & (NS - 1);
  const int f  = t >> 4;
  const int b0 = blockIdx.x * NS;

  const float* ws[5] = {w1, w3, w5, w7, w9};
  const float* cs[5] = {c1, c3, c5, c7, c9};

  float dot = 0.0f;
  process_input<0, 12>(x0, ws, cs, dw, tile, t, s, f, b0, dot);  // pep
  process_input<1,  7>(x1, ws, cs, dw, tile, t, s, f, b0, dot);  // a1
  process_input<2,  8>(x2, ws, cs, dw, tile, t, s, f, b0, dot);  // a2
  process_input<3, 22>(x3, ws, cs, dw, tile, t, s, f, b0, dot);  // a3
  process_input<4,  6>(x4, ws, cs, dw, tile, t, s, f, b0, dot);  // b1
  process_input<5,  7>(x5, ws, cs, dw, tile, t, s, f, b0, dot);  // b2
  process_input<6, 23>(x6, ws, cs, dw, tile, t, s, f, b0, dot);  // b3

  red[t] = dot;
  __syncthreads();
  if (t < NS) {
    float sum = db[0];
    #pragma unroll
    for (int j = 0; j < NF; ++j) sum += red[t + NS * j];
    out[b0 + t] = 1.0f / (1.0f + expf(-sum));
  }
}

} // namespace

extern "C" void kernel_launch(void* const* d_in, const int* in_sizes, int n_in,
                              void* d_out, int out_size, void* d_ws, size_t ws_size,
                              hipStream_t stream) {
  // First 7 inputs: pep, a1, a2, a3, b1, b2, b3 (both orderings agree).
  const float* xs[7];
  for (int i = 0; i < 7; ++i) xs[i] = (const float*)d_in[i];

  // Remaining: identify by unique flat sizes (robust to dict vs signature order).
  const float* wptr[5] = {nullptr, nullptr, nullptr, nullptr, nullptr};
  const float* cptr[5] = {nullptr, nullptr, nullptr, nullptr, nullptr};
  const float* dw = nullptr;
  const float* db = nullptr;
  int c_seen = 0;
  for (int idx = 7; idx < n_in; ++idx) {
    const int sz = in_sizes[idx];
    const float* p = (const float*)d_in[idx];
    if (sz == 1) { db = p; }
    else if (sz == NF * 35) { dw = p; }                 // 560
    else if (sz == 7 * NF) { cptr[c_seen++] = p; }      // 112, appear in k order
    else {
      const int k = sz / (7 * NF * ED);                 // 1,3,5,7,9
      wptr[(k - 1) / 2] = p;
    }
  }

  float* out = (float*)d_out;
  const int B = 16384;
  dim3 grid(B / NS), block(NT);
  hipLaunchKernelGGL(nettcr_fused, grid, block, 0, stream,
                     xs[0], xs[1], xs[2], xs[3], xs[4], xs[5], xs[6],
                     wptr[0], cptr[0], wptr[1], cptr[1], wptr[2], cptr[2],
                     wptr[3], cptr[3], wptr[4], cptr[4], dw, db, out);
}

// Round 3
// 98.556 us; speedup vs baseline: 5.5142x; 5.5142x over previous
//
#include <hip/hip_runtime.h>
#include <cmath>

namespace {

using bf16x8 = __attribute__((ext_vector_type(8))) short;
using f32x4  = __attribute__((ext_vector_type(4))) float;

constexpr int NT = 192;        // 3 waves per block
constexpr int NS = 16;         // samples per block (one MFMA M-tile)
constexpr int LPAD = 31;       // fixed padded position count (Lmax=23 + 8)
constexpr int TILE_BYTES = NS * LPAD * 32 * 2;  // 31744 B

__device__ __forceinline__ short f2bf(float f) {  // RNE float->bf16
  unsigned u = __float_as_uint(f);
  unsigned r = (u + 0x7FFFu + ((u >> 16) & 1u)) >> 16;
  return (short)r;
}

// Granule index for tile[s][q][cq*8..cq*8+7] (16B granules).
// Structurally bijective swizzle: only permutes cq within the (s,q) quad
// (blocks 4u..4u+3, u = s*31+q, are disjoint), so collisions are impossible.
// Reads (fixed q, lanes (s,cq)): 2 lanes per 16B slot -> free (m136).
// Writes (fixed s, q varying): all 8 slots per 8 consecutive q -> ~3-way.
__device__ __forceinline__ int gidx(int s, int q, int cq) {
  return (s * 31 + q) * 4 + ((cq ^ ((s >> 1) + (q >> 1))) & 3);
}

// A-fragment: lane holds x[s=lane&15][col q][c = (lane>>4)*8 .. +7].
__device__ __forceinline__ bf16x8 ldcol(const char* smem, int s, int cq, int q) {
  return *(const bf16x8*)(smem + (gidx(s, q, cq) << 4));
}

// One wave-role: kernel sizes K1 (and optional K2 < K1, window nested).
template<int K1, int K2>
__device__ __forceinline__ void run_role(
    const char* __restrict__ smem, int s, int cq, int f,
    const float* __restrict__ wk1, const float* __restrict__ ck1,
    const float* __restrict__ wk2, const float* __restrict__ ck2,
    const float* __restrict__ dw, int i, int L, f32x4& dvec)
{
  constexpr int KK1 = (K1 - 1) / 2;
  constexpr int KK2 = (K2 > 0) ? (K2 - 1) / 2 : 0;

  // B-operand fragments: lane = filter f, holds w[f][cq*8+j][t], j=0..7.
  bf16x8 wf1[K1];
  #pragma unroll
  for (int t = 0; t < K1; ++t) {
    const float* wp = wk1 + (size_t)((i * 16 + f) * 32 + cq * 8) * K1 + t;
    bf16x8 v;
    #pragma unroll
    for (int j = 0; j < 8; ++j) v[j] = f2bf(wp[(size_t)j * K1]);
    wf1[t] = v;
  }
  bf16x8 wf2[(K2 > 0) ? K2 : 1];
  if constexpr (K2 > 0) {
    #pragma unroll
    for (int t = 0; t < K2; ++t) {
      const float* wp = wk2 + (size_t)((i * 16 + f) * 32 + cq * 8) * K2 + t;
      bf16x8 v;
      #pragma unroll
      for (int j = 0; j < 8; ++j) v[j] = f2bf(wp[(size_t)j * K2]);
      wf2[t] = v;
    }
  }

  const float b1 = ck1[i * 16 + f];
  float b2 = 0.f;
  if constexpr (K2 > 0) b2 = ck2[i * 16 + f];

  f32x4 mx1 = {0.f, 0.f, 0.f, 0.f};   // ReLU folded into max-init 0
  f32x4 mx2 = {0.f, 0.f, 0.f, 0.f};

  // Sliding window invariant: af[(P+t)%K1] holds padded col P + 4 - KK1 + t.
  bf16x8 af[K1];
  #pragma unroll
  for (int j = 0; j < K1; ++j) af[j] = ldcol(smem, s, cq, 4 - KK1 + j);

  auto body = [&](int p, int pi) {
    f32x4 aa = {b1, b1, b1, b1};      // even-tap chain (bias pre-added)
    f32x4 ab = {0.f, 0.f, 0.f, 0.f};  // odd-tap chain (ILP split)
    #pragma unroll
    for (int t = 0; t < K1; ++t) {
      if (t & 1)
        ab = __builtin_amdgcn_mfma_f32_16x16x32_bf16(af[(pi + t) % K1], wf1[t], ab, 0, 0, 0);
      else
        aa = __builtin_amdgcn_mfma_f32_16x16x32_bf16(af[(pi + t) % K1], wf1[t], aa, 0, 0, 0);
    }
    if constexpr (K2 > 0) {
      f32x4 ac = {b2, b2, b2, b2};
      #pragma unroll
      for (int t = 0; t < K2; ++t)
        ac = __builtin_amdgcn_mfma_f32_16x16x32_bf16(af[(pi + (KK1 - KK2) + t) % K1], wf2[t], ac, 0, 0, 0);
      #pragma unroll
      for (int r = 0; r < 4; ++r) mx2[r] = fmaxf(mx2[r], ac[r]);
    }
    #pragma unroll
    for (int r = 0; r < 4; ++r) mx1[r] = fmaxf(mx1[r], aa[r] + ab[r]);
    if (p + pi + 1 < L)                         // slide: col for position p+pi+1
      af[pi] = ldcol(smem, s, cq, p + pi + 5 + KK1);
  };

  int p = 0;
  for (; p + K1 <= L; p += K1) {                // K1-blocked -> static rotation idx
    #pragma unroll
    for (int pi = 0; pi < K1; ++pi) body(p, pi);
  }
  #pragma unroll
  for (int pi = 0; pi < K1 - 1; ++pi)           // tail (rem <= K1-1)
    if (p + pi < L) body(p, pi);

  {
    const float dv1 = dw[(i * 5 + KK1) * 16 + f];
    #pragma unroll
    for (int r = 0; r < 4; ++r) dvec[r] = fmaf(mx1[r], dv1, dvec[r]);
  }
  if constexpr (K2 > 0) {
    const float dv2 = dw[(i * 5 + KK2) * 16 + f];
    #pragma unroll
    for (int r = 0; r < 4; ++r) dvec[r] = fmaf(mx2[r], dv2, dvec[r]);
  }
}

__global__ __launch_bounds__(NT, 3) void nettcr_mfma(
    const float* __restrict__ x0, const float* __restrict__ x1,
    const float* __restrict__ x2, const float* __restrict__ x3,
    const float* __restrict__ x4, const float* __restrict__ x5,
    const float* __restrict__ x6,
    const float* __restrict__ w1, const float* __restrict__ c1,
    const float* __restrict__ w3, const float* __restrict__ c3,
    const float* __restrict__ w5, const float* __restrict__ c5,
    const float* __restrict__ w7, const float* __restrict__ c7,
    const float* __restrict__ w9, const float* __restrict__ c9,
    const float* __restrict__ dw, const float* __restrict__ db,
    float* __restrict__ out)
{
  __shared__ __align__(16) char smem[TILE_BYTES];
  const int tid  = threadIdx.x;
  const int lane = tid & 63;
  const int wid  = tid >> 6;
  const int s    = lane & 15;      // A-side: sample row
  const int cq   = lane >> 4;      // k-quadrant: channels cq*8..+7
  const int f    = lane & 15;      // B-side: filter col
  const int b0   = blockIdx.x * NS;

  f32x4 dvec = {0.f, 0.f, 0.f, 0.f};

  for (int i = 0; i < 7; ++i) {
    const float* xi; int L;
    switch (i) {
      case 0: xi = x0; L = 12; break;
      case 1: xi = x1; L = 7;  break;
      case 2: xi = x2; L = 8;  break;
      case 3: xi = x3; L = 22; break;
      case 4: xi = x4; L = 6;  break;
      case 5: xi = x5; L = 7;  break;
      default: xi = x6; L = 23; break;
    }
    __syncthreads();   // all waves done reading previous tile
    // stage: x[b0+ss][c][l] (f32) -> tile[ss][l+4][c] (bf16), swizzled writes
    for (int e = tid; e < 64 * L; e += NT) {
      const int l  = e % L;
      const int rr = e / L;
      const int cg = rr & 3;
      const int ss = rr >> 2;
      const float* src = xi + ((size_t)(b0 + ss) * 32 + cg * 8) * L + l;
      bf16x8 pk;
      #pragma unroll
      for (int j = 0; j < 8; ++j) pk[j] = f2bf(src[(size_t)j * L]);
      *(bf16x8*)(smem + (gidx(ss, l + 4, cg) << 4)) = pk;
    }
    // zero the 4+4 SAME-padding columns (branchless taps)
    for (int e = tid; e < 512; e += NT) {
      const int q8 = e & 7;
      const int q  = (q8 < 4) ? q8 : (L + q8);
      const int cg = (e >> 3) & 3;
      const int ss = e >> 5;
      bf16x8 z = {0, 0, 0, 0, 0, 0, 0, 0};
      *(bf16x8*)(smem + (gidx(ss, q, cg) << 4)) = z;
    }
    __syncthreads();   // tile ready

    if (wid == 0)
      run_role<9, 0>(smem, s, cq, f, w9, c9, nullptr, nullptr, dw, i, L, dvec);
    else if (wid == 1)
      run_role<7, 1>(smem, s, cq, f, w7, c7, w1, c1, dw, i, L, dvec);
    else
      run_role<5, 3>(smem, s, cq, f, w5, c5, w3, c3, dw, i, L, dvec);
  }

  // reduce dot partials over 3 waves x 16 filters  (D row = (lane>>4)*4 + r)
  __syncthreads();
  float* red = (float*)smem;
  *(f32x4*)&red[(wid * 64 + lane) * 4] = dvec;
  __syncthreads();
  if (tid < 16) {
    float sum = db[0];
    const int g4 = tid >> 2, r = tid & 3;
    for (int w = 0; w < 3; ++w)
      #pragma unroll
      for (int f2 = 0; f2 < 16; ++f2)
        sum += red[(w * 64 + g4 * 16 + f2) * 4 + r];
    out[b0 + tid] = 1.0f / (1.0f + expf(-sum));
  }
}

} // namespace

extern "C" void kernel_launch(void* const* d_in, const int* in_sizes, int n_in,
                              void* d_out, int out_size, void* d_ws, size_t ws_size,
                              hipStream_t stream) {
  (void)d_ws; (void)ws_size; (void)out_size;
  const float* xs[7];
  for (int i = 0; i < 7; ++i) xs[i] = (const float*)d_in[i];

  const float* wptr[5] = {nullptr, nullptr, nullptr, nullptr, nullptr};
  const float* cptr[5] = {nullptr, nullptr, nullptr, nullptr, nullptr};
  const float* dw = nullptr;
  const float* db = nullptr;
  int c_seen = 0;
  for (int idx = 7; idx < n_in; ++idx) {
    const int sz = in_sizes[idx];
    const float* p = (const float*)d_in[idx];
    if (sz == 1) { db = p; }
    else if (sz == 16 * 35) { dw = p; }                 // 560
    else if (sz == 7 * 16) { cptr[c_seen++] = p; }      // 112, appear in k order
    else {
      const int k = sz / (7 * 16 * 32);                 // 1,3,5,7,9
      wptr[(k - 1) / 2] = p;
    }
  }

  float* out = (float*)d_out;
  const int B = 16384;
  dim3 grid(B / NS), block(NT);
  hipLaunchKernelGGL(nettcr_mfma, grid, block, 0, stream,
                     xs[0], xs[1], xs[2], xs[3], xs[4], xs[5], xs[6],
                     wptr[0], cptr[0], wptr[1], cptr[1], wptr[2], cptr[2],
                     wptr[3], cptr[3], wptr[4], cptr[4], dw, db, out);
}